// Round 1
// baseline (139.450 us; speedup 1.0000x reference)
//
#include <hip/hip_runtime.h>
#include <math.h>

#define N0 2048
#define D0 3
#define N1 1024
#define D1 5
#define TILE 16

// ws layout (float offsets):
//   kn0   [N0*9]            @ 0
//   inv0  [N0*9]            @ 18432
//   kn1   [N1*25]           @ 36864
//   inv1  [N1*25]           @ 62464
//   part0 [(N0/16)^2=16384] @ 88064
//   part1 [(N1/16)^2=4096]  @ 104448
// total 108544 floats = 434 KB

__global__ void prep_kernel(const float* __restrict__ k0, const float* __restrict__ k1,
                            float* __restrict__ kn0, float* __restrict__ inv0,
                            float* __restrict__ kn1, float* __restrict__ inv1) {
    int t = blockIdx.x * blockDim.x + threadIdx.x;
    if (t < N0) {
        // ---- 3x3: normalize + adjugate inverse (fp64) ----
        double a[9];
        double ss = 0.0;
#pragma unroll
        for (int e = 0; e < 9; ++e) { a[e] = (double)k0[t * 9 + e]; ss += a[e] * a[e]; }
        double rn = 1.0 / (sqrt(ss) + 1e-8);
#pragma unroll
        for (int e = 0; e < 9; ++e) a[e] *= rn;
        double c00 = a[4] * a[8] - a[5] * a[7];
        double c01 = -(a[3] * a[8] - a[5] * a[6]);
        double c02 = a[3] * a[7] - a[4] * a[6];
        double det = a[0] * c00 + a[1] * c01 + a[2] * c02;
        double id = 1.0 / det;
        double iv[9];
        iv[0] = c00 * id;
        iv[1] = (a[2] * a[7] - a[1] * a[8]) * id;
        iv[2] = (a[1] * a[5] - a[2] * a[4]) * id;
        iv[3] = c01 * id;
        iv[4] = (a[0] * a[8] - a[2] * a[6]) * id;
        iv[5] = (a[2] * a[3] - a[0] * a[5]) * id;
        iv[6] = c02 * id;
        iv[7] = (a[1] * a[6] - a[0] * a[7]) * id;
        iv[8] = (a[0] * a[4] - a[1] * a[3]) * id;
#pragma unroll
        for (int e = 0; e < 9; ++e) {
            kn0[t * 9 + e] = (float)a[e];
            inv0[t * 9 + e] = (float)iv[e];
        }
    } else {
        int u = t - N0;
        if (u < N1) {
            // ---- 5x5: normalize + Gauss-Jordan w/ partial pivoting (fp64) ----
            double A[5][5], B[5][5];
            double ss = 0.0;
            for (int r = 0; r < 5; ++r)
                for (int c = 0; c < 5; ++c) {
                    double v = (double)k1[u * 25 + r * 5 + c];
                    A[r][c] = v;
                    ss += v * v;
                }
            double rn = 1.0 / (sqrt(ss) + 1e-8);
            for (int r = 0; r < 5; ++r)
                for (int c = 0; c < 5; ++c) {
                    A[r][c] *= rn;
                    kn1[u * 25 + r * 5 + c] = (float)A[r][c];
                    B[r][c] = (r == c) ? 1.0 : 0.0;
                }
            for (int k = 0; k < 5; ++k) {
                // partial pivot
                int p = k;
                double best = fabs(A[k][k]);
                for (int r = k + 1; r < 5; ++r) {
                    double v = fabs(A[r][k]);
                    if (v > best) { best = v; p = r; }
                }
                if (p != k) {
                    for (int c = 0; c < 5; ++c) {
                        double tA = A[k][c]; A[k][c] = A[p][c]; A[p][c] = tA;
                        double tB = B[k][c]; B[k][c] = B[p][c]; B[p][c] = tB;
                    }
                }
                double piv = 1.0 / A[k][k];
                for (int c = 0; c < 5; ++c) { A[k][c] *= piv; B[k][c] *= piv; }
                for (int r = 0; r < 5; ++r) {
                    if (r == k) continue;
                    double f = A[r][k];
                    for (int c = 0; c < 5; ++c) {
                        A[r][c] -= f * A[k][c];
                        B[r][c] -= f * B[k][c];
                    }
                }
            }
            for (int r = 0; r < 5; ++r)
                for (int c = 0; c < 5; ++c)
                    inv1[u * 25 + r * 5 + c] = (float)B[r][c];
        }
    }
}

// Lower-triangle pair sums, d=3. Grid (128,128); block 256 = 16x16 pairs.
__global__ __launch_bounds__(256) void pairs3_kernel(const float* __restrict__ inv0,
                                                     const float* __restrict__ kn0,
                                                     float* __restrict__ partial) {
    __shared__ float sInv[TILE][9];
    __shared__ float sKn[TILE][9];
    int bj = blockIdx.x, bi = blockIdx.y;
    int tid = threadIdx.x;
    float contrib = 0.0f;
    if (bi >= bj) {
        if (tid < TILE * 9) {
            int r = tid / 9, e = tid % 9;
            sInv[r][e] = inv0[(bi * TILE + r) * 9 + e];
            sKn[r][e] = kn0[(bj * TILE + r) * 9 + e];
        }
        __syncthreads();
        int ti = tid / TILE, tj = tid % TILE;
        int i = bi * TILE + ti, j = bj * TILE + tj;
        if (i > j) {
            float a[9], b[9];
#pragma unroll
            for (int e = 0; e < 9; ++e) { a[e] = sInv[ti][e]; b[e] = sKn[tj][e]; }
            float s = 0.0f;
#pragma unroll
            for (int r = 0; r < 3; ++r) {
#pragma unroll
                for (int c = 0; c < 3; ++c) {
                    float m = a[r * 3 + 0] * b[0 * 3 + c];
                    m = fmaf(a[r * 3 + 1], b[1 * 3 + c], m);
                    m = fmaf(a[r * 3 + 2], b[2 * 3 + c], m);
                    float dlt = ((r == c) ? 1.0f : 0.0f) - m;
                    s = fmaf(dlt, dlt, s);
                }
            }
            contrib = fmaxf(0.0f, 1.0f - sqrtf(s));
        }
    }
    // block reduce (all blocks, incl. skipped, must write their partial slot)
#pragma unroll
    for (int off = 32; off; off >>= 1) contrib += __shfl_down(contrib, off);
    __shared__ float wsum[4];
    if ((tid & 63) == 0) wsum[tid >> 6] = contrib;
    __syncthreads();
    if (tid == 0) partial[bi * gridDim.x + bj] = wsum[0] + wsum[1] + wsum[2] + wsum[3];
}

// Lower-triangle pair sums, d=5. Grid (64,64); block 256 = 16x16 pairs.
__global__ __launch_bounds__(256) void pairs5_kernel(const float* __restrict__ inv1,
                                                     const float* __restrict__ kn1,
                                                     float* __restrict__ partial) {
    __shared__ float sInv[TILE][25];
    __shared__ float sKn[TILE][25];
    int bj = blockIdx.x, bi = blockIdx.y;
    int tid = threadIdx.x;
    float contrib = 0.0f;
    if (bi >= bj) {
        for (int e = tid; e < TILE * 25; e += 256) {
            int r = e / 25, c = e % 25;
            sInv[r][c] = inv1[(bi * TILE + r) * 25 + c];
            sKn[r][c] = kn1[(bj * TILE + r) * 25 + c];
        }
        __syncthreads();
        int ti = tid / TILE, tj = tid % TILE;
        int i = bi * TILE + ti, j = bj * TILE + tj;
        if (i > j) {
            float a[25], b[25];
#pragma unroll
            for (int e = 0; e < 25; ++e) { a[e] = sInv[ti][e]; b[e] = sKn[tj][e]; }
            float s = 0.0f;
#pragma unroll
            for (int r = 0; r < 5; ++r) {
#pragma unroll
                for (int c = 0; c < 5; ++c) {
                    float m = a[r * 5 + 0] * b[0 * 5 + c];
#pragma unroll
                    for (int k = 1; k < 5; ++k) m = fmaf(a[r * 5 + k], b[k * 5 + c], m);
                    float dlt = ((r == c) ? 1.0f : 0.0f) - m;
                    s = fmaf(dlt, dlt, s);
                }
            }
            contrib = fmaxf(0.0f, 1.0f - sqrtf(s));
        }
    }
#pragma unroll
    for (int off = 32; off; off >>= 1) contrib += __shfl_down(contrib, off);
    __shared__ float wsum[4];
    if ((tid & 63) == 0) wsum[tid >> 6] = contrib;
    __syncthreads();
    if (tid == 0) partial[bi * gridDim.x + bj] = wsum[0] + wsum[1] + wsum[2] + wsum[3];
}

__global__ void finalize_kernel(const float* __restrict__ part0, int np0,
                                const float* __restrict__ part1, int np1,
                                float* __restrict__ out) {
    int tid = threadIdx.x;
    double s0 = 0.0, s1 = 0.0;
    for (int x = tid; x < np0; x += 256) s0 += (double)part0[x];
    for (int x = tid; x < np1; x += 256) s1 += (double)part1[x];
#pragma unroll
    for (int off = 32; off; off >>= 1) {
        s0 += __shfl_down(s0, off);
        s1 += __shfl_down(s1, off);
    }
    __shared__ double w0[4], w1[4];
    if ((tid & 63) == 0) { w0[tid >> 6] = s0; w1[tid >> 6] = s1; }
    __syncthreads();
    if (tid == 0) {
        double S0 = w0[0] + w0[1] + w0[2] + w0[3];
        double S1 = w1[0] + w1[1] + w1[2] + w1[3];
        // final = (2*S0/(n0(n0-1)) + 2*S1/(n1(n1-1))) / 2
        double res = S0 / ((double)N0 * (double)(N0 - 1)) +
                     S1 / ((double)N1 * (double)(N1 - 1));
        out[0] = (float)res;
    }
}

extern "C" void kernel_launch(void* const* d_in, const int* in_sizes, int n_in,
                              void* d_out, int out_size, void* d_ws, size_t ws_size,
                              hipStream_t stream) {
    const float* k0 = (const float*)d_in[0];   // (2048,3,3)
    const float* k1 = (const float*)d_in[1];   // (1024,5,5)
    float* out = (float*)d_out;

    float* ws = (float*)d_ws;
    float* kn0 = ws;                    // 18432
    float* inv0 = kn0 + N0 * 9;         // 18432
    float* kn1 = inv0 + N0 * 9;         // 25600
    float* inv1 = kn1 + N1 * 25;        // 25600
    float* part0 = inv1 + N1 * 25;      // 16384
    float* part1 = part0 + (N0 / TILE) * (N0 / TILE);  // 4096

    int totalPrep = N0 + N1;
    prep_kernel<<<(totalPrep + 255) / 256, 256, 0, stream>>>(k0, k1, kn0, inv0, kn1, inv1);

    dim3 g3(N0 / TILE, N0 / TILE);
    pairs3_kernel<<<g3, 256, 0, stream>>>(inv0, kn0, part0);

    dim3 g5(N1 / TILE, N1 / TILE);
    pairs5_kernel<<<g5, 256, 0, stream>>>(inv1, kn1, part1);

    int np0 = (N0 / TILE) * (N0 / TILE);
    int np1 = (N1 / TILE) * (N1 / TILE);
    finalize_kernel<<<1, 256, 0, stream>>>(part0, np0, part1, np1, out);
}

// Round 2
// 81.450 us; speedup vs baseline: 1.7121x; 1.7121x over previous
//
#include <hip/hip_runtime.h>
#include <math.h>

#define N0 2048
#define N1 1024
#define M0T 32                    // 2048 / 64-tile
#define M1T 32                    // 1024 / 32-tile
#define NB0 (M0T * (M0T + 1) / 2) // 528 lower-tri blocks, layer 0
#define NB1 (M1T * (M1T + 1) / 2) // 528 lower-tri blocks, layer 1
#define NBTOT (NB0 + NB1)         // 1056

// ws layout (float offsets):
//   kn0   [N0*9]   inv0 [N0*9]   kn1 [N1*25]   inv1 [N1*25]   partial [NBTOT]

__global__ void prep_kernel(const float* __restrict__ k0, const float* __restrict__ k1,
                            float* __restrict__ kn0, float* __restrict__ inv0,
                            float* __restrict__ kn1, float* __restrict__ inv1) {
    int t = blockIdx.x * blockDim.x + threadIdx.x;
    if (t < N0) {
        // ---- 3x3: normalize + adjugate inverse (fp64, static indexing) ----
        double a[9];
        double ss = 0.0;
#pragma unroll
        for (int e = 0; e < 9; ++e) { a[e] = (double)k0[t * 9 + e]; ss += a[e] * a[e]; }
        double rn = 1.0 / (sqrt(ss) + 1e-8);
#pragma unroll
        for (int e = 0; e < 9; ++e) a[e] *= rn;
        double c00 = a[4] * a[8] - a[5] * a[7];
        double c01 = -(a[3] * a[8] - a[5] * a[6]);
        double c02 = a[3] * a[7] - a[4] * a[6];
        double det = a[0] * c00 + a[1] * c01 + a[2] * c02;
        double id = 1.0 / det;
        double iv[9];
        iv[0] = c00 * id;
        iv[1] = (a[2] * a[7] - a[1] * a[8]) * id;
        iv[2] = (a[1] * a[5] - a[2] * a[4]) * id;
        iv[3] = c01 * id;
        iv[4] = (a[0] * a[8] - a[2] * a[6]) * id;
        iv[5] = (a[2] * a[3] - a[0] * a[5]) * id;
        iv[6] = c02 * id;
        iv[7] = (a[1] * a[6] - a[0] * a[7]) * id;
        iv[8] = (a[0] * a[4] - a[1] * a[3]) * id;
#pragma unroll
        for (int e = 0; e < 9; ++e) {
            kn0[t * 9 + e] = (float)a[e];
            inv0[t * 9 + e] = (float)iv[e];
        }
    } else {
        int u = t - N0;
        if (u < N1) {
            // ---- 5x5: normalize + BRANCHLESS Gauss-Jordan w/ partial pivoting ----
            // All loops have compile-time bounds -> fully unrolled -> static
            // indexing -> arrays live in registers (no scratch spills).
            double A[5][5], B[5][5];
            double ss = 0.0;
#pragma unroll
            for (int r = 0; r < 5; ++r)
#pragma unroll
                for (int c = 0; c < 5; ++c) {
                    double v = (double)k1[u * 25 + r * 5 + c];
                    A[r][c] = v;
                    ss += v * v;
                }
            double rn = 1.0 / (sqrt(ss) + 1e-8);
#pragma unroll
            for (int r = 0; r < 5; ++r)
#pragma unroll
                for (int c = 0; c < 5; ++c) {
                    A[r][c] *= rn;
                    kn1[u * 25 + r * 5 + c] = (float)A[r][c];
                    B[r][c] = (r == c) ? 1.0 : 0.0;
                }
#pragma unroll
            for (int k = 0; k < 5; ++k) {
                // branchless partial pivot: conditionally swap each candidate
                // row into the pivot slot (bubble-max). Indices all static.
#pragma unroll
                for (int r = k + 1; r < 5; ++r) {
                    bool sw = fabs(A[r][k]) > fabs(A[k][k]);
#pragma unroll
                    for (int c = k; c < 5; ++c) {   // cols < k are zero in rows >= k
                        double Ar = A[r][c], Ak = A[k][c];
                        A[r][c] = sw ? Ak : Ar;
                        A[k][c] = sw ? Ar : Ak;
                    }
#pragma unroll
                    for (int c = 0; c < 5; ++c) {
                        double Br = B[r][c], Bk = B[k][c];
                        B[r][c] = sw ? Bk : Br;
                        B[k][c] = sw ? Br : Bk;
                    }
                }
                double piv = 1.0 / A[k][k];
#pragma unroll
                for (int c = k; c < 5; ++c) A[k][c] *= piv;
#pragma unroll
                for (int c = 0; c < 5; ++c) B[k][c] *= piv;
#pragma unroll
                for (int r = 0; r < 5; ++r) {
                    if (r == k) continue;
                    double f = A[r][k];
#pragma unroll
                    for (int c = k; c < 5; ++c) A[r][c] -= f * A[k][c];
#pragma unroll
                    for (int c = 0; c < 5; ++c) B[r][c] -= f * B[k][c];
                }
            }
#pragma unroll
            for (int r = 0; r < 5; ++r)
#pragma unroll
                for (int c = 0; c < 5; ++c)
                    inv1[u * 25 + r * 5 + c] = (float)B[r][c];
        }
    }
}

// Fused pair-distance kernel, triangular grid.
//   blocks [0, NB0):      layer 0 (d=3), 64x64 tile, 4x4 pairs/thread
//   blocks [NB0, NBTOT):  layer 1 (d=5), 32x32 tile, 2x2 pairs/thread
__global__ __launch_bounds__(256) void pairs_kernel(const float* __restrict__ inv0,
                                                    const float* __restrict__ kn0,
                                                    const float* __restrict__ inv1,
                                                    const float* __restrict__ kn1,
                                                    float* __restrict__ partial) {
    __shared__ float sA[800];  // layer0: 64*9=576; layer1: 32*25=800
    __shared__ float sB[800];
    int tid = threadIdx.x;
    float contrib = 0.0f;

    if (blockIdx.x < NB0) {
        // ---------------- layer 0: d=3, 64-tile ----------------
        int t = blockIdx.x;
        int bi = (int)((sqrtf(8.0f * t + 1.0f) - 1.0f) * 0.5f);
        while ((bi + 1) * (bi + 2) / 2 <= t) ++bi;
        while (bi * (bi + 1) / 2 > t) --bi;
        int bj = t - bi * (bi + 1) / 2;

        for (int e = tid; e < 64 * 9; e += 256) {
            sA[e] = inv0[bi * 576 + e];
            sB[e] = kn0[bj * 576 + e];
        }
        __syncthreads();

        int ti = tid >> 4, tj = tid & 15;
        int ibase = bi * 64 + ti * 4, jbase = bj * 64 + tj * 4;
#pragma unroll
        for (int u = 0; u < 4; ++u) {
            float a[9];
#pragma unroll
            for (int e = 0; e < 9; ++e) a[e] = sA[(ti * 4 + u) * 9 + e];
#pragma unroll
            for (int v = 0; v < 4; ++v) {
                float b[9];
#pragma unroll
                for (int e = 0; e < 9; ++e) b[e] = sB[(tj * 4 + v) * 9 + e];
                float s = 0.0f;
#pragma unroll
                for (int r = 0; r < 3; ++r)
#pragma unroll
                    for (int c = 0; c < 3; ++c) {
                        float m = a[r * 3 + 0] * b[c];
                        m = fmaf(a[r * 3 + 1], b[3 + c], m);
                        m = fmaf(a[r * 3 + 2], b[6 + c], m);
                        float d = ((r == c) ? 1.0f : 0.0f) - m;
                        s = fmaf(d, d, s);
                    }
                bool take = ((ibase + u) > (jbase + v)) && (s < 1.0f);
                contrib += take ? (1.0f - sqrtf(s)) : 0.0f;
            }
        }
    } else {
        // ---------------- layer 1: d=5, 32-tile ----------------
        int t = blockIdx.x - NB0;
        int bi = (int)((sqrtf(8.0f * t + 1.0f) - 1.0f) * 0.5f);
        while ((bi + 1) * (bi + 2) / 2 <= t) ++bi;
        while (bi * (bi + 1) / 2 > t) --bi;
        int bj = t - bi * (bi + 1) / 2;

        for (int e = tid; e < 32 * 25; e += 256) {
            sA[e] = inv1[bi * 800 + e];
            sB[e] = kn1[bj * 800 + e];
        }
        __syncthreads();

        int ti = tid >> 4, tj = tid & 15;
        int ibase = bi * 32 + ti * 2, jbase = bj * 32 + tj * 2;
#pragma unroll
        for (int u = 0; u < 2; ++u) {
            float a[25];
#pragma unroll
            for (int e = 0; e < 25; ++e) a[e] = sA[(ti * 2 + u) * 25 + e];
#pragma unroll
            for (int v = 0; v < 2; ++v) {
                float b[25];
#pragma unroll
                for (int e = 0; e < 25; ++e) b[e] = sB[(tj * 2 + v) * 25 + e];
                float s = 0.0f;
#pragma unroll
                for (int r = 0; r < 5; ++r)
#pragma unroll
                    for (int c = 0; c < 5; ++c) {
                        float m = a[r * 5 + 0] * b[c];
#pragma unroll
                        for (int k = 1; k < 5; ++k) m = fmaf(a[r * 5 + k], b[k * 5 + c], m);
                        float d = ((r == c) ? 1.0f : 0.0f) - m;
                        s = fmaf(d, d, s);
                    }
                bool take = ((ibase + u) > (jbase + v)) && (s < 1.0f);
                contrib += take ? (1.0f - sqrtf(s)) : 0.0f;
            }
        }
    }

    // block reduction -> one partial per block (every block writes its slot)
#pragma unroll
    for (int off = 32; off; off >>= 1) contrib += __shfl_down(contrib, off);
    __shared__ float wsum[4];
    if ((tid & 63) == 0) wsum[tid >> 6] = contrib;
    __syncthreads();
    if (tid == 0) partial[blockIdx.x] = wsum[0] + wsum[1] + wsum[2] + wsum[3];
}

__global__ void finalize_kernel(const float* __restrict__ partial, float* __restrict__ out) {
    int tid = threadIdx.x;
    double s0 = 0.0, s1 = 0.0;
    for (int x = tid; x < NB0; x += 256) s0 += (double)partial[x];
    for (int x = NB0 + tid; x < NBTOT; x += 256) s1 += (double)partial[x];
#pragma unroll
    for (int off = 32; off; off >>= 1) {
        s0 += __shfl_down(s0, off);
        s1 += __shfl_down(s1, off);
    }
    __shared__ double w0[4], w1[4];
    if ((tid & 63) == 0) { w0[tid >> 6] = s0; w1[tid >> 6] = s1; }
    __syncthreads();
    if (tid == 0) {
        double S0 = w0[0] + w0[1] + w0[2] + w0[3];
        double S1 = w1[0] + w1[1] + w1[2] + w1[3];
        // final = (2*S0/(n0(n0-1)) + 2*S1/(n1(n1-1))) / 2
        double res = S0 / ((double)N0 * (double)(N0 - 1)) +
                     S1 / ((double)N1 * (double)(N1 - 1));
        out[0] = (float)res;
    }
}

extern "C" void kernel_launch(void* const* d_in, const int* in_sizes, int n_in,
                              void* d_out, int out_size, void* d_ws, size_t ws_size,
                              hipStream_t stream) {
    const float* k0 = (const float*)d_in[0];   // (2048,3,3)
    const float* k1 = (const float*)d_in[1];   // (1024,5,5)
    float* out = (float*)d_out;

    float* ws = (float*)d_ws;
    float* kn0 = ws;                    // 18432
    float* inv0 = kn0 + N0 * 9;         // 18432
    float* kn1 = inv0 + N0 * 9;         // 25600
    float* inv1 = kn1 + N1 * 25;        // 25600
    float* partial = inv1 + N1 * 25;    // 1056

    int totalPrep = N0 + N1;
    prep_kernel<<<(totalPrep + 255) / 256, 256, 0, stream>>>(k0, k1, kn0, inv0, kn1, inv1);

    pairs_kernel<<<NBTOT, 256, 0, stream>>>(inv0, kn0, inv1, kn1, partial);

    finalize_kernel<<<1, 256, 0, stream>>>(partial, out);
}

// Round 3
// 69.753 us; speedup vs baseline: 1.9992x; 1.1677x over previous
//
#include <hip/hip_runtime.h>
#include <math.h>

#define N0 2048
#define N1 1024
#define M0T 32                    // 2048 / 64-tile
#define M1T 32                    // 1024 / 32-tile
#define NB0 (M0T * (M0T + 1) / 2) // 528 lower-tri blocks, layer 0
#define NB1 (M1T * (M1T + 1) / 2) // 528 lower-tri blocks, layer 1
#define NBTOT (NB0 + NB1)         // 1056

// ws layout (float offsets):
//   kn0 [N0*9]  inv0 [N0*9]  kn1 [N1*25]  inv1 [N1*25]  partial [NBTOT]

// All-fp32 prep: normalize + invert + one Newton polish (X <- X(2I - A X)).
// Register footprint ~70 VGPRs -> no scratch spills; block=64 for CU spread.
__global__ __launch_bounds__(64) void prep_kernel(const float* __restrict__ k0,
                                                  const float* __restrict__ k1,
                                                  float* __restrict__ kn0,
                                                  float* __restrict__ inv0,
                                                  float* __restrict__ kn1,
                                                  float* __restrict__ inv1) {
    int t = blockIdx.x * blockDim.x + threadIdx.x;
    if (t < N0) {
        // ---- 3x3: normalize + adjugate inverse + Newton (fp32) ----
        float a[9];
        float ss = 0.0f;
#pragma unroll
        for (int e = 0; e < 9; ++e) { a[e] = k0[t * 9 + e]; ss = fmaf(a[e], a[e], ss); }
        float rn = 1.0f / (sqrtf(ss) + 1e-8f);
#pragma unroll
        for (int e = 0; e < 9; ++e) a[e] *= rn;
        float c00 = a[4] * a[8] - a[5] * a[7];
        float c01 = -(a[3] * a[8] - a[5] * a[6]);
        float c02 = a[3] * a[7] - a[4] * a[6];
        float det = a[0] * c00 + a[1] * c01 + a[2] * c02;
        float id = 1.0f / det;
        float x[9];
        x[0] = c00 * id;
        x[1] = (a[2] * a[7] - a[1] * a[8]) * id;
        x[2] = (a[1] * a[5] - a[2] * a[4]) * id;
        x[3] = c01 * id;
        x[4] = (a[0] * a[8] - a[2] * a[6]) * id;
        x[5] = (a[2] * a[3] - a[0] * a[5]) * id;
        x[6] = c02 * id;
        x[7] = (a[1] * a[6] - a[0] * a[7]) * id;
        x[8] = (a[0] * a[4] - a[1] * a[3]) * id;
        // Newton polish: x <- x(2I - a x)
        float r[9];
#pragma unroll
        for (int i = 0; i < 3; ++i)
#pragma unroll
            for (int j = 0; j < 3; ++j) {
                float m = a[i * 3 + 0] * x[0 * 3 + j];
                m = fmaf(a[i * 3 + 1], x[1 * 3 + j], m);
                m = fmaf(a[i * 3 + 2], x[2 * 3 + j], m);
                r[i * 3 + j] = ((i == j) ? 2.0f : 0.0f) - m;
            }
        float xn[9];
#pragma unroll
        for (int i = 0; i < 3; ++i)
#pragma unroll
            for (int j = 0; j < 3; ++j) {
                float m = x[i * 3 + 0] * r[0 * 3 + j];
                m = fmaf(x[i * 3 + 1], r[1 * 3 + j], m);
                m = fmaf(x[i * 3 + 2], r[2 * 3 + j], m);
                xn[i * 3 + j] = m;
            }
#pragma unroll
        for (int e = 0; e < 9; ++e) {
            kn0[t * 9 + e] = a[e];
            inv0[t * 9 + e] = xn[e];
        }
    } else {
        int u = t - N0;
        if (u < N1) {
            // ---- 5x5: normalize + branchless GJ w/ partial pivot + Newton (fp32) ----
            float A[5][5], B[5][5], K[5][5];
            float ss = 0.0f;
#pragma unroll
            for (int r = 0; r < 5; ++r)
#pragma unroll
                for (int c = 0; c < 5; ++c) {
                    float v = k1[u * 25 + r * 5 + c];
                    A[r][c] = v;
                    ss = fmaf(v, v, ss);
                }
            float rn = 1.0f / (sqrtf(ss) + 1e-8f);
#pragma unroll
            for (int r = 0; r < 5; ++r)
#pragma unroll
                for (int c = 0; c < 5; ++c) {
                    A[r][c] *= rn;
                    K[r][c] = A[r][c];
                    kn1[u * 25 + r * 5 + c] = A[r][c];
                    B[r][c] = (r == c) ? 1.0f : 0.0f;
                }
#pragma unroll
            for (int k = 0; k < 5; ++k) {
                // branchless bubble-max pivot (static indices only)
#pragma unroll
                for (int r = k + 1; r < 5; ++r) {
                    bool sw = fabsf(A[r][k]) > fabsf(A[k][k]);
#pragma unroll
                    for (int c = k; c < 5; ++c) {
                        float Ar = A[r][c], Ak = A[k][c];
                        A[r][c] = sw ? Ak : Ar;
                        A[k][c] = sw ? Ar : Ak;
                    }
#pragma unroll
                    for (int c = 0; c < 5; ++c) {
                        float Br = B[r][c], Bk = B[k][c];
                        B[r][c] = sw ? Bk : Br;
                        B[k][c] = sw ? Br : Bk;
                    }
                }
                float piv = 1.0f / A[k][k];
#pragma unroll
                for (int c = k; c < 5; ++c) A[k][c] *= piv;
#pragma unroll
                for (int c = 0; c < 5; ++c) B[k][c] *= piv;
#pragma unroll
                for (int r = 0; r < 5; ++r) {
                    if (r == k) continue;
                    float f = A[r][k];
#pragma unroll
                    for (int c = k; c < 5; ++c) A[r][c] = fmaf(-f, A[k][c], A[r][c]);
#pragma unroll
                    for (int c = 0; c < 5; ++c) B[r][c] = fmaf(-f, B[k][c], B[r][c]);
                }
            }
            // Newton polish: B <- B(2I - K B)
            float R[5][5];
#pragma unroll
            for (int i = 0; i < 5; ++i)
#pragma unroll
                for (int j = 0; j < 5; ++j) {
                    float m = K[i][0] * B[0][j];
#pragma unroll
                    for (int k = 1; k < 5; ++k) m = fmaf(K[i][k], B[k][j], m);
                    R[i][j] = ((i == j) ? 2.0f : 0.0f) - m;
                }
#pragma unroll
            for (int i = 0; i < 5; ++i)
#pragma unroll
                for (int j = 0; j < 5; ++j) {
                    float m = B[i][0] * R[0][j];
#pragma unroll
                    for (int k = 1; k < 5; ++k) m = fmaf(B[i][k], R[k][j], m);
                    inv1[u * 25 + i * 5 + j] = m;
                }
        }
    }
}

// Fused pair-distance kernel, triangular grid.
//   blocks [0, NB0):      layer 0 (d=3), 64x64 tile, 4x4 pairs/thread
//   blocks [NB0, NBTOT):  layer 1 (d=5), 32x32 tile, 2x2 pairs/thread
// Loop order: preload all a-fragments to registers, then v{load b; u{compute}}
// -> LDS read count 180->72 (layer0), 150->100 (layer1).
__global__ __launch_bounds__(256) void pairs_kernel(const float* __restrict__ inv0,
                                                    const float* __restrict__ kn0,
                                                    const float* __restrict__ inv1,
                                                    const float* __restrict__ kn1,
                                                    float* __restrict__ partial) {
    __shared__ float sA[800];  // layer0: 64*9=576; layer1: 32*25=800
    __shared__ float sB[800];
    int tid = threadIdx.x;
    float contrib = 0.0f;

    if (blockIdx.x < NB0) {
        // ---------------- layer 0: d=3, 64-tile ----------------
        int t = blockIdx.x;
        int bi = (int)((sqrtf(8.0f * t + 1.0f) - 1.0f) * 0.5f);
        while ((bi + 1) * (bi + 2) / 2 <= t) ++bi;
        while (bi * (bi + 1) / 2 > t) --bi;
        int bj = t - bi * (bi + 1) / 2;

        for (int e = tid; e < 64 * 9; e += 256) {
            sA[e] = inv0[bi * 576 + e];
            sB[e] = kn0[bj * 576 + e];
        }
        __syncthreads();

        int ti = tid >> 4, tj = tid & 15;
        int ibase = bi * 64 + ti * 4, jbase = bj * 64 + tj * 4;
        float a[4][9];
#pragma unroll
        for (int u = 0; u < 4; ++u)
#pragma unroll
            for (int e = 0; e < 9; ++e) a[u][e] = sA[(ti * 4 + u) * 9 + e];
#pragma unroll
        for (int v = 0; v < 4; ++v) {
            float b[9];
#pragma unroll
            for (int e = 0; e < 9; ++e) b[e] = sB[(tj * 4 + v) * 9 + e];
#pragma unroll
            for (int u = 0; u < 4; ++u) {
                float s = 0.0f;
#pragma unroll
                for (int r = 0; r < 3; ++r)
#pragma unroll
                    for (int c = 0; c < 3; ++c) {
                        float m = a[u][r * 3 + 0] * b[c];
                        m = fmaf(a[u][r * 3 + 1], b[3 + c], m);
                        m = fmaf(a[u][r * 3 + 2], b[6 + c], m);
                        float d = ((r == c) ? 1.0f : 0.0f) - m;
                        s = fmaf(d, d, s);
                    }
                bool take = ((ibase + u) > (jbase + v)) && (s < 1.0f);
                contrib += take ? (1.0f - sqrtf(s)) : 0.0f;
            }
        }
    } else {
        // ---------------- layer 1: d=5, 32-tile ----------------
        int t = blockIdx.x - NB0;
        int bi = (int)((sqrtf(8.0f * t + 1.0f) - 1.0f) * 0.5f);
        while ((bi + 1) * (bi + 2) / 2 <= t) ++bi;
        while (bi * (bi + 1) / 2 > t) --bi;
        int bj = t - bi * (bi + 1) / 2;

        for (int e = tid; e < 32 * 25; e += 256) {
            sA[e] = inv1[bi * 800 + e];
            sB[e] = kn1[bj * 800 + e];
        }
        __syncthreads();

        int ti = tid >> 4, tj = tid & 15;
        int ibase = bi * 32 + ti * 2, jbase = bj * 32 + tj * 2;
        float a[2][25];
#pragma unroll
        for (int u = 0; u < 2; ++u)
#pragma unroll
            for (int e = 0; e < 25; ++e) a[u][e] = sA[(ti * 2 + u) * 25 + e];
#pragma unroll
        for (int v = 0; v < 2; ++v) {
            float b[25];
#pragma unroll
            for (int e = 0; e < 25; ++e) b[e] = sB[(tj * 2 + v) * 25 + e];
#pragma unroll
            for (int u = 0; u < 2; ++u) {
                float s = 0.0f;
#pragma unroll
                for (int r = 0; r < 5; ++r)
#pragma unroll
                    for (int c = 0; c < 5; ++c) {
                        float m = a[u][r * 5 + 0] * b[c];
#pragma unroll
                        for (int k = 1; k < 5; ++k) m = fmaf(a[u][r * 5 + k], b[k * 5 + c], m);
                        float d = ((r == c) ? 1.0f : 0.0f) - m;
                        s = fmaf(d, d, s);
                    }
                bool take = ((ibase + u) > (jbase + v)) && (s < 1.0f);
                contrib += take ? (1.0f - sqrtf(s)) : 0.0f;
            }
        }
    }

    // block reduction -> one partial per block (every block writes its slot)
#pragma unroll
    for (int off = 32; off; off >>= 1) contrib += __shfl_down(contrib, off);
    __shared__ float wsum[4];
    if ((tid & 63) == 0) wsum[tid >> 6] = contrib;
    __syncthreads();
    if (tid == 0) partial[blockIdx.x] = wsum[0] + wsum[1] + wsum[2] + wsum[3];
}

__global__ void finalize_kernel(const float* __restrict__ partial, float* __restrict__ out) {
    int tid = threadIdx.x;
    double s0 = 0.0, s1 = 0.0;
    for (int x = tid; x < NB0; x += 256) s0 += (double)partial[x];
    for (int x = NB0 + tid; x < NBTOT; x += 256) s1 += (double)partial[x];
#pragma unroll
    for (int off = 32; off; off >>= 1) {
        s0 += __shfl_down(s0, off);
        s1 += __shfl_down(s1, off);
    }
    __shared__ double w0[4], w1[4];
    if ((tid & 63) == 0) { w0[tid >> 6] = s0; w1[tid >> 6] = s1; }
    __syncthreads();
    if (tid == 0) {
        double S0 = w0[0] + w0[1] + w0[2] + w0[3];
        double S1 = w1[0] + w1[1] + w1[2] + w1[3];
        // final = (2*S0/(n0(n0-1)) + 2*S1/(n1(n1-1))) / 2
        double res = S0 / ((double)N0 * (double)(N0 - 1)) +
                     S1 / ((double)N1 * (double)(N1 - 1));
        out[0] = (float)res;
    }
}

extern "C" void kernel_launch(void* const* d_in, const int* in_sizes, int n_in,
                              void* d_out, int out_size, void* d_ws, size_t ws_size,
                              hipStream_t stream) {
    const float* k0 = (const float*)d_in[0];   // (2048,3,3)
    const float* k1 = (const float*)d_in[1];   // (1024,5,5)
    float* out = (float*)d_out;

    float* ws = (float*)d_ws;
    float* kn0 = ws;                    // 18432
    float* inv0 = kn0 + N0 * 9;         // 18432
    float* kn1 = inv0 + N0 * 9;         // 25600
    float* inv1 = kn1 + N1 * 25;        // 25600
    float* partial = inv1 + N1 * 25;    // 1056

    int totalPrep = N0 + N1;            // 3072 threads, block=64 -> 48 blocks
    prep_kernel<<<(totalPrep + 63) / 64, 64, 0, stream>>>(k0, k1, kn0, inv0, kn1, inv1);

    pairs_kernel<<<NBTOT, 256, 0, stream>>>(inv0, kn0, inv1, kn1, partial);

    finalize_kernel<<<1, 256, 0, stream>>>(partial, out);
}